// Round 12
// baseline (354.252 us; speedup 1.0000x reference)
//
#include <hip/hip_runtime.h>

typedef unsigned short u16;
typedef unsigned int u32;
typedef __attribute__((ext_vector_type(4))) float f32x4;
typedef __attribute__((ext_vector_type(8))) __bf16 bf16x8;
typedef __attribute__((ext_vector_type(4))) _Float16 f16x4;
typedef __attribute__((ext_vector_type(4))) u16 u16x4;
typedef __attribute__((ext_vector_type(4))) u32 u32x4;
typedef __attribute__((ext_vector_type(2))) u32 u32x2;

#define D_ 1024
#define S_ 2048
#define B_ 4
#define H_ 16
#define HD_ 64
#define M_ 8192
#define LDP 72
#define QSCALE 0.18033688011112042591f /* 0.125 * log2(e) */

__device__ __forceinline__ u16 f2bf(float f) {
  u32 u = __float_as_uint(f);
  u += 0x7fffu + ((u >> 16) & 1u);
  return (u16)(u >> 16);
}

__device__ __forceinline__ float max3f(float a, float b, float c) {
  return fmaxf(fmaxf(a, b), c);  // clang fuses to v_max3_f32
}

// async 16B global->LDS DMA; LDS dest = wave-uniform base + lane*16 (linear!)
__device__ __forceinline__ void gload_lds16(const void* g, void* l) {
  __builtin_amdgcn_global_load_lds((const __attribute__((address_space(1))) void*)g,
                                   (__attribute__((address_space(3))) void*)l, 16, 0, 0);
}

// ---------------- cast x (fp32 -> bf16) ----------------
__global__ __launch_bounds__(256) void cast_x_kernel(const float* __restrict__ x,
                                                     u16* __restrict__ xb) {
  int i = (blockIdx.x * 256 + threadIdx.x) * 4;
  f32x4 v = *(const f32x4*)(x + i);
  u16x4 o = {f2bf(v[0]), f2bf(v[1]), f2bf(v[2]), f2bf(v[3])};
  *(u16x4*)(xb + i) = o;
}

// ---------------- transpose+cast weights: Wt[n][k] = bf16(W[k][n]) ----------------
__global__ __launch_bounds__(256) void wtrans_kernel(const float* __restrict__ Wq, const float* __restrict__ Wk,
                                                     const float* __restrict__ Wv, const float* __restrict__ Wo,
                                                     u16* __restrict__ Wqt, u16* __restrict__ Wkt,
                                                     u16* __restrict__ Wvt, u16* __restrict__ Wot) {
  __shared__ float lds[64][65];
  const float* W = blockIdx.z == 0 ? Wq : blockIdx.z == 1 ? Wk : blockIdx.z == 2 ? Wv : Wo;
  u16* Wt       = blockIdx.z == 0 ? Wqt : blockIdx.z == 1 ? Wkt : blockIdx.z == 2 ? Wvt : Wot;
  int k0 = blockIdx.x * 64, n0 = blockIdx.y * 64;
  int tr = threadIdx.x >> 6, tc = threadIdx.x & 63;
#pragma unroll
  for (int i = 0; i < 16; ++i)
    lds[tr + i * 4][tc] = W[(size_t)(k0 + tr + i * 4) * D_ + n0 + tc];
  __syncthreads();
#pragma unroll
  for (int i = 0; i < 16; ++i)
    Wt[(size_t)(n0 + tr + i * 4) * D_ + k0 + tc] = f2bf(lds[tc][tr + i * 4]);
}

// ---------------- shared 128x128 GEMM mainloop (global_load_lds staging, XOR swizzle) ----------------
__device__ __forceinline__ void gemm_main(const u16* __restrict__ A, const u16* __restrict__ Bt,
                                          u16* As, u16* Bs, int row0, int col0, f32x4 acc[4][4]) {
  const int tid = threadIdx.x;
  const int lane = tid & 63, wave = tid >> 6;
  const int wr = wave >> 1, wc = wave & 1;
  const int l15 = lane & 15, lg = lane >> 4;
  const int sr8 = lane >> 3;        // row within this wave's 8-row chunk (= r&7)
  const int scx = (lane & 7) ^ sr8; // pre-swizzled source k-chunk
#pragma unroll 1
  for (int k0 = 0; k0 < D_; k0 += 64) {
    // issue async stages: 4 wave-chunks of 8 rows for A and B each
#pragma unroll
    for (int it = 0; it < 4; ++it) {
      int rbase = (it * 4 + wave) * 8;
      int r = rbase + sr8;
      gload_lds16(A + (size_t)(row0 + r) * D_ + k0 + scx * 8, As + rbase * 64);
      gload_lds16(Bt + (size_t)(col0 + r) * D_ + k0 + scx * 8, Bs + rbase * 64);
    }
    __syncthreads();  // drains vmcnt -> DMA writes visible; syncs waves
#pragma unroll
    for (int kk = 0; kk < 64; kk += 32) {
      const int cb = kk >> 3;  // 0 or 4
      bf16x8 af[4], bf[4];
#pragma unroll
      for (int m = 0; m < 4; ++m) {
        int row = wr * 64 + m * 16 + l15;
        af[m] = *(const bf16x8*)(As + row * 64 + (((cb + lg) ^ (l15 & 7)) << 3));
      }
#pragma unroll
      for (int n = 0; n < 4; ++n) {
        int row = wc * 64 + n * 16 + l15;
        bf[n] = *(const bf16x8*)(Bs + row * 64 + (((cb + lg) ^ (l15 & 7)) << 3));
      }
#pragma unroll
      for (int m = 0; m < 4; ++m)
#pragma unroll
        for (int n = 0; n < 4; ++n)
          acc[m][n] = __builtin_amdgcn_mfma_f32_16x16x32_bf16(af[m], bf[n], acc[m][n], 0, 0, 0);
    }
    __syncthreads();  // readers done before next iteration's DMA writes
  }
}

// ---------------- QKV projection GEMM (1D grid, XCD-clustered swizzle) ----------------
__global__ __launch_bounds__(256) void qkv_gemm_kernel(const u16* __restrict__ xb,
                                                       const u16* __restrict__ Wqt, const u16* __restrict__ Wkt,
                                                       const u16* __restrict__ Wvt,
                                                       u16* __restrict__ Qb, u16* __restrict__ Kb,
                                                       _Float16* __restrict__ Vt) {
  __shared__ u16 As[128 * 64];
  __shared__ u16 Bs[128 * 64];
  int lin = blockIdx.x;
  int xcd = lin & 7, pos = lin >> 3;      // pos in [0,192)
  int mode = pos / 64;                    // z outer
  int rem = pos & 63;
  int by = xcd * 8 + (rem >> 3);          // row-panel
  int bx = rem & 7;                       // col-tile
  const u16* Bt = mode == 0 ? Wqt : mode == 1 ? Wkt : Wvt;
  f32x4 acc[4][4] = {};
  int row0 = by * 128, col0 = bx * 128;
  gemm_main(xb, Bt, As, Bs, row0, col0, acc);
  int lane = threadIdx.x & 63, wave = threadIdx.x >> 6;
  int wr = wave >> 1, wc = wave & 1, l15 = lane & 15, lg = lane >> 4;
  int rbase = row0 + wr * 64 + lg * 4, cbase = col0 + wc * 64 + l15;
  if (mode == 2) {
#pragma unroll
    for (int m = 0; m < 4; ++m) {
      int row = rbase + m * 16;
      int b = row >> 11, s = row & (S_ - 1);
#pragma unroll
      for (int n = 0; n < 4; ++n) {
        int col = cbase + n * 16;
        int h = col >> 6, hd = col & 63;
        f16x4 vv = {(_Float16)acc[m][n][0], (_Float16)acc[m][n][1],
                    (_Float16)acc[m][n][2], (_Float16)acc[m][n][3]};
        *(f16x4*)(Vt + ((size_t)((b << 4) + h) * HD_ + hd) * S_ + s) = vv;
      }
    }
  } else {
    u16* dst = mode == 0 ? Qb : Kb;
    float scl = mode == 0 ? QSCALE : 1.0f;
#pragma unroll
    for (int m = 0; m < 4; ++m)
#pragma unroll
      for (int n = 0; n < 4; ++n) {
        int col = cbase + n * 16;
#pragma unroll
        for (int r = 0; r < 4; ++r) {
          int row = rbase + m * 16 + r;
          dst[(size_t)row * D_ + col] = f2bf(acc[m][n][r] * scl);
        }
      }
  }
}

// ---------------- fused causal flash attention, v10: single-buffer LDS for 8 blocks/CU ----------------
// v7 per-tile body (padded LDS, immediate-offset reads, reg staging) with:
//   * SINGLE K/V buffer (18KB LDS) -> 8 blocks/CU capacity
//   * 2048 blocks (one per qblk x bh), LPT (big qblk first), XCD clustering
//   * scalar lsum (no osum MFMA, r8 proved neutral) to fit 64 VGPR
//   * __launch_bounds__(256,8) -> 64-VGPR budget -> 32 waves/CU
// Tile loop: [barrier: readers done] write(t) [barrier: visible] issue loads(t+1); compute(t).
__global__ __launch_bounds__(256, 8) void attn_kernel(const u16* __restrict__ Qb, const u16* __restrict__ Kb,
                                                      const _Float16* __restrict__ Vt, u16* __restrict__ attnb) {
  __shared__ u16 Ks[64][LDP];       // [kv][hd]
  __shared__ _Float16 Vs[64][LDP];  // [hd][kv]
  const int tid = threadIdx.x;
  const int wave = tid >> 6, lane = tid & 63;
  const int l15 = lane & 15, lg = lane >> 4;
  const int lin = blockIdx.x;
  const int xcd = lin & 7, slot = lin >> 3;   // slot 0..255
  const int qblk = 31 - (slot >> 3);          // LPT: biggest first
  const int bh = (slot & 7) * 8 + xcd;        // bh&7 == xcd
  const int b = bh >> 4, h = bh & 15;
  const int ntiles = qblk + 1;
  const int q0 = qblk * 64 + wave * 16;

  const int srow = tid >> 3;
  const int scol = (tid & 7) * 8;  // u16/f16 elems (16B)
  const u16* Kg = Kb + (size_t)(b * S_) * D_ + h * HD_;
  const _Float16* Vg = Vt + (size_t)bh * HD_ * S_;

  const u16* Qrow = Qb + (size_t)(b * S_ + q0 + l15) * D_ + h * HD_;
  bf16x8 qf0 = *(const bf16x8*)(Qrow + lg * 8);
  bf16x8 qf1 = *(const bf16x8*)(Qrow + 32 + lg * 8);

  float m = -1e30f, lsum = 0.f;
  f32x4 o[4] = {};
  u32x4 kreg0, kreg1, vreg0, vreg1;

  // prologue: tile 0 -> regs
  kreg0 = *(const u32x4*)(Kg + (size_t)(srow) * D_ + scol);
  kreg1 = *(const u32x4*)(Kg + (size_t)(32 + srow) * D_ + scol);
  vreg0 = *(const u32x4*)(Vg + (size_t)srow * S_ + scol);
  vreg1 = *(const u32x4*)(Vg + (size_t)(32 + srow) * S_ + scol);

#pragma unroll 1
  for (int t = 0; t < ntiles; ++t) {
    __syncthreads();  // previous tile's readers done -> safe to overwrite
    *(u32x4*)(&Ks[srow][scol]) = kreg0;
    *(u32x4*)(&Ks[32 + srow][scol]) = kreg1;
    *(u32x4*)(&Vs[srow][scol]) = vreg0;
    *(u32x4*)(&Vs[32 + srow][scol]) = vreg1;
    __syncthreads();  // writes visible
    // issue global loads for tile t+1 (drain under compute)
    if (t + 1 < ntiles) {
      int kv0n = (t + 1) * 64;
      kreg0 = *(const u32x4*)(Kg + (size_t)(kv0n + srow) * D_ + scol);
      kreg1 = *(const u32x4*)(Kg + (size_t)(kv0n + 32 + srow) * D_ + scol);
      vreg0 = *(const u32x4*)(Vg + (size_t)srow * S_ + kv0n + scol);
      vreg1 = *(const u32x4*)(Vg + (size_t)(32 + srow) * S_ + kv0n + scol);
    }
    // ---- QK^T: 4 subtiles of 16 kv ----
    f32x4 s[4];
    __builtin_amdgcn_s_setprio(1);
#pragma unroll
    for (int j = 0; j < 4; ++j) {
      bf16x8 kf0 = *(const bf16x8*)(&Ks[j * 16 + l15][lg * 8]);
      bf16x8 kf1 = *(const bf16x8*)(&Ks[j * 16 + l15][32 + lg * 8]);
      f32x4 z = {0.f, 0.f, 0.f, 0.f};
      z = __builtin_amdgcn_mfma_f32_16x16x32_bf16(kf0, qf0, z, 0, 0, 0);
      z = __builtin_amdgcn_mfma_f32_16x16x32_bf16(kf1, qf1, z, 0, 0, 0);
      s[j] = z;
    }
    __builtin_amdgcn_s_setprio(0);
    // ---- mask (diagonal tile only) ----
    if (t == ntiles - 1) {
      int qr = wave * 16 + l15;
#pragma unroll
      for (int j = 0; j < 4; ++j)
#pragma unroll
        for (int r = 0; r < 4; ++r)
          if (j * 16 + lg * 4 + r > qr) s[j][r] = -1e30f;
    }
    // ---- online softmax (max3 tree + one cross-lane reduce per 64 kv) ----
    float x0 = max3f(s[0][0], s[0][1], s[0][2]);
    float x1 = max3f(s[0][3], s[1][0], s[1][1]);
    float x2 = max3f(s[1][2], s[1][3], s[2][0]);
    float x3 = max3f(s[2][1], s[2][2], s[2][3]);
    float x4 = max3f(s[3][0], s[3][1], s[3][2]);
    float tmax = fmaxf(max3f(x0, x1, x2), max3f(x3, x4, s[3][3]));
    tmax = fmaxf(tmax, __shfl_xor(tmax, 16));
    tmax = fmaxf(tmax, __shfl_xor(tmax, 32));
    if (!__all(tmax - m <= 8.f)) {  // defer-max (T13)
      float nm = fmaxf(m, tmax);
      float alpha = exp2f(m - nm);
      m = nm;
      lsum *= alpha;
#pragma unroll
      for (int hf = 0; hf < 4; ++hf) o[hf] *= alpha;
    }
    f16x4 pb[4];
#pragma unroll
    for (int j = 0; j < 4; ++j) {
      float p0 = exp2f(s[j][0] - m), p1 = exp2f(s[j][1] - m);
      float p2 = exp2f(s[j][2] - m), p3 = exp2f(s[j][3] - m);
      lsum += (p0 + p1) + (p2 + p3);
      u32 lo = __builtin_bit_cast(u32, __builtin_amdgcn_cvt_pkrtz(p0, p1));
      u32 hi = __builtin_bit_cast(u32, __builtin_amdgcn_cvt_pkrtz(p2, p3));
      pb[j] = __builtin_bit_cast(f16x4, (u32x2){lo, hi});
    }
    // ---- PV: o[hf] += V^T[hf] * P ----
    __builtin_amdgcn_s_setprio(1);
#pragma unroll
    for (int j = 0; j < 4; ++j) {
#pragma unroll
      for (int hf = 0; hf < 4; ++hf) {
        f16x4 vf = *(const f16x4*)(&Vs[hf * 16 + l15][j * 16 + lg * 4]);
        o[hf] = __builtin_amdgcn_mfma_f32_16x16x16f16(vf, pb[j], o[hf], 0, 0, 0);
      }
    }
    __builtin_amdgcn_s_setprio(0);
  }
  // ---- epilogue: reduce lsum across lane-groups, normalize, store ----
  lsum += __shfl_xor(lsum, 16);
  lsum += __shfl_xor(lsum, 32);
  float inv = 1.0f / lsum;
  u16* Orow = attnb + (size_t)(b * S_ + q0 + l15) * D_ + h * HD_ + lg * 4;
#pragma unroll
  for (int hf = 0; hf < 4; ++hf) {
    u16x4 ov = {f2bf(o[hf][0] * inv), f2bf(o[hf][1] * inv),
                f2bf(o[hf][2] * inv), f2bf(o[hf][3] * inv)};
    *(u16x4*)(Orow + hf * 16) = ov;
  }
}

// ---------------- output projection GEMM (fp32 out + bias, XCD-clustered swizzle) ----------------
__global__ __launch_bounds__(256) void out_gemm_kernel(const u16* __restrict__ attnb, const u16* __restrict__ Wot,
                                                       const float* __restrict__ bo, float* __restrict__ outp) {
  __shared__ u16 As[128 * 64];
  __shared__ u16 Bs[128 * 64];
  int lin = blockIdx.x;
  int xcd = lin & 7, pos = lin >> 3;  // pos in [0,64)
  int by = xcd * 8 + (pos >> 3);
  int bx = pos & 7;
  f32x4 acc[4][4] = {};
  int row0 = by * 128, col0 = bx * 128;
  gemm_main(attnb, Wot, As, Bs, row0, col0, acc);
  int lane = threadIdx.x & 63, wave = threadIdx.x >> 6;
  int wr = wave >> 1, wc = wave & 1, l15 = lane & 15, lg = lane >> 4;
  int rbase = row0 + wr * 64 + lg * 4, cbase = col0 + wc * 64 + l15;
#pragma unroll
  for (int n = 0; n < 4; ++n) {
    float bn = bo[cbase + n * 16];
#pragma unroll
    for (int m = 0; m < 4; ++m)
#pragma unroll
      for (int r = 0; r < 4; ++r)
        outp[(size_t)(rbase + m * 16 + r) * D_ + cbase + n * 16] = acc[m][n][r] + bn;
  }
}

extern "C" void kernel_launch(void* const* d_in, const int* in_sizes, int n_in,
                              void* d_out, int out_size, void* d_ws, size_t ws_size,
                              hipStream_t stream) {
  const float* x  = (const float*)d_in[0];
  const float* Wq = (const float*)d_in[1];
  const float* Wk = (const float*)d_in[2];
  const float* Wv = (const float*)d_in[3];
  const float* Wo = (const float*)d_in[4];
  const float* bo = (const float*)d_in[5];
  float* outp = (float*)d_out;

  char* ws = (char*)d_ws;
  u16* xb        = (u16*)(ws);                          // 16 MiB
  u16* Wqt       = (u16*)(ws + ((size_t)16 << 20));     // 2 MiB
  u16* Wkt       = (u16*)(ws + ((size_t)18 << 20));
  u16* Wvt       = (u16*)(ws + ((size_t)20 << 20));
  u16* Wot       = (u16*)(ws + ((size_t)22 << 20));
  u16* Qb        = (u16*)(ws + ((size_t)24 << 20));     // 16 MiB
  u16* Kb        = (u16*)(ws + ((size_t)40 << 20));     // 16 MiB
  _Float16* Vt   = (_Float16*)(ws + ((size_t)56 << 20));// 16 MiB
  u16* attnb     = (u16*)(ws + ((size_t)72 << 20));     // 16 MiB

  cast_x_kernel<<<dim3(M_ * D_ / (256 * 4)), dim3(256), 0, stream>>>(x, xb);
  wtrans_kernel<<<dim3(16, 16, 4), dim3(256), 0, stream>>>(Wq, Wk, Wv, Wo, Wqt, Wkt, Wvt, Wot);
  qkv_gemm_kernel<<<dim3(1536), dim3(256), 0, stream>>>(xb, Wqt, Wkt, Wvt, Qb, Kb, Vt);
  attn_kernel<<<dim3(2048), dim3(256), 0, stream>>>(Qb, Kb, Vt, attnb);
  out_gemm_kernel<<<dim3(512), dim3(256), 0, stream>>>(attnb, Wot, bo, outp);
}

// Round 13
// 208.370 us; speedup vs baseline: 1.7001x; 1.7001x over previous
//
#include <hip/hip_runtime.h>

typedef unsigned short u16;
typedef unsigned int u32;
typedef __attribute__((ext_vector_type(4))) float f32x4;
typedef __attribute__((ext_vector_type(8))) __bf16 bf16x8;
typedef __attribute__((ext_vector_type(4))) _Float16 f16x4;
typedef __attribute__((ext_vector_type(4))) u16 u16x4;
typedef __attribute__((ext_vector_type(4))) u32 u32x4;
typedef __attribute__((ext_vector_type(2))) u32 u32x2;

#define D_ 1024
#define S_ 2048
#define B_ 4
#define H_ 16
#define HD_ 64
#define M_ 8192
#define LDP 72
#define QSCALE 0.18033688011112042591f /* 0.125 * log2(e) */

__device__ __forceinline__ u16 f2bf(float f) {
  u32 u = __float_as_uint(f);
  u += 0x7fffu + ((u >> 16) & 1u);
  return (u16)(u >> 16);
}

__device__ __forceinline__ float max3f(float a, float b, float c) {
  return fmaxf(fmaxf(a, b), c);  // clang fuses to v_max3_f32
}

// async 16B global->LDS DMA; LDS dest = wave-uniform base + lane*16 (linear!)
__device__ __forceinline__ void gload_lds16(const void* g, void* l) {
  __builtin_amdgcn_global_load_lds((const __attribute__((address_space(1))) void*)g,
                                   (__attribute__((address_space(3))) void*)l, 16, 0, 0);
}

// ---------------- fused prep: cast x (fp32->bf16) + transpose+cast weights ----------------
// blocks [0, 8192): cast x; blocks [8192, 9216): wtrans (z = pos/256, k = (pos&255)>>4, n = pos&15)
__global__ __launch_bounds__(256) void prep_kernel(const float* __restrict__ x, u16* __restrict__ xb,
                                                   const float* __restrict__ Wq, const float* __restrict__ Wk,
                                                   const float* __restrict__ Wv, const float* __restrict__ Wo,
                                                   u16* __restrict__ Wqt, u16* __restrict__ Wkt,
                                                   u16* __restrict__ Wvt, u16* __restrict__ Wot) {
  __shared__ float lds[64][65];
  int lin = blockIdx.x;
  if (lin < 8192) {
    int i = (lin * 256 + threadIdx.x) * 4;
    f32x4 v = *(const f32x4*)(x + i);
    u16x4 o = {f2bf(v[0]), f2bf(v[1]), f2bf(v[2]), f2bf(v[3])};
    *(u16x4*)(xb + i) = o;
    return;
  }
  int pos = lin - 8192;
  int z = pos >> 8, rem = pos & 255;
  const float* W = z == 0 ? Wq : z == 1 ? Wk : z == 2 ? Wv : Wo;
  u16* Wt       = z == 0 ? Wqt : z == 1 ? Wkt : z == 2 ? Wvt : Wot;
  int k0 = (rem >> 4) * 64, n0 = (rem & 15) * 64;
  int tr = threadIdx.x >> 6, tc = threadIdx.x & 63;
#pragma unroll
  for (int i = 0; i < 16; ++i)
    lds[tr + i * 4][tc] = W[(size_t)(k0 + tr + i * 4) * D_ + n0 + tc];
  __syncthreads();
#pragma unroll
  for (int i = 0; i < 16; ++i)
    Wt[(size_t)(n0 + tr + i * 4) * D_ + k0 + tc] = f2bf(lds[tc][tr + i * 4]);
}

// ---------------- shared 128x128 GEMM mainloop (global_load_lds staging, XOR swizzle) ----------------
__device__ __forceinline__ void gemm_main(const u16* __restrict__ A, const u16* __restrict__ Bt,
                                          u16* As, u16* Bs, int row0, int col0, f32x4 acc[4][4]) {
  const int tid = threadIdx.x;
  const int lane = tid & 63, wave = tid >> 6;
  const int wr = wave >> 1, wc = wave & 1;
  const int l15 = lane & 15, lg = lane >> 4;
  const int sr8 = lane >> 3;        // row within this wave's 8-row chunk (= r&7)
  const int scx = (lane & 7) ^ sr8; // pre-swizzled source k-chunk
#pragma unroll 1
  for (int k0 = 0; k0 < D_; k0 += 64) {
    // issue async stages: 4 wave-chunks of 8 rows for A and B each
#pragma unroll
    for (int it = 0; it < 4; ++it) {
      int rbase = (it * 4 + wave) * 8;
      int r = rbase + sr8;
      gload_lds16(A + (size_t)(row0 + r) * D_ + k0 + scx * 8, As + rbase * 64);
      gload_lds16(Bt + (size_t)(col0 + r) * D_ + k0 + scx * 8, Bs + rbase * 64);
    }
    __syncthreads();  // drains vmcnt -> DMA writes visible; syncs waves
#pragma unroll
    for (int kk = 0; kk < 64; kk += 32) {
      const int cb = kk >> 3;  // 0 or 4
      bf16x8 af[4], bf[4];
#pragma unroll
      for (int m = 0; m < 4; ++m) {
        int row = wr * 64 + m * 16 + l15;
        af[m] = *(const bf16x8*)(As + row * 64 + (((cb + lg) ^ (l15 & 7)) << 3));
      }
#pragma unroll
      for (int n = 0; n < 4; ++n) {
        int row = wc * 64 + n * 16 + l15;
        bf[n] = *(const bf16x8*)(Bs + row * 64 + (((cb + lg) ^ (l15 & 7)) << 3));
      }
#pragma unroll
      for (int m = 0; m < 4; ++m)
#pragma unroll
        for (int n = 0; n < 4; ++n)
          acc[m][n] = __builtin_amdgcn_mfma_f32_16x16x32_bf16(af[m], bf[n], acc[m][n], 0, 0, 0);
    }
    __syncthreads();  // readers done before next iteration's DMA writes
  }
}

// ---------------- QKV projection GEMM (1D grid, XCD-clustered swizzle) ----------------
__global__ __launch_bounds__(256) void qkv_gemm_kernel(const u16* __restrict__ xb,
                                                       const u16* __restrict__ Wqt, const u16* __restrict__ Wkt,
                                                       const u16* __restrict__ Wvt,
                                                       u16* __restrict__ Qb, u16* __restrict__ Kb,
                                                       _Float16* __restrict__ Vt) {
  __shared__ u16 As[128 * 64];
  __shared__ u16 Bs[128 * 64];
  int lin = blockIdx.x;
  int xcd = lin & 7, pos = lin >> 3;      // pos in [0,192)
  int mode = pos / 64;                    // z outer
  int rem = pos & 63;
  int by = xcd * 8 + (rem >> 3);          // row-panel
  int bx = rem & 7;                       // col-tile
  const u16* Bt = mode == 0 ? Wqt : mode == 1 ? Wkt : Wvt;
  f32x4 acc[4][4] = {};
  int row0 = by * 128, col0 = bx * 128;
  gemm_main(xb, Bt, As, Bs, row0, col0, acc);
  int lane = threadIdx.x & 63, wave = threadIdx.x >> 6;
  int wr = wave >> 1, wc = wave & 1, l15 = lane & 15, lg = lane >> 4;
  int rbase = row0 + wr * 64 + lg * 4, cbase = col0 + wc * 64 + l15;
  if (mode == 2) {
#pragma unroll
    for (int m = 0; m < 4; ++m) {
      int row = rbase + m * 16;
      int b = row >> 11, s = row & (S_ - 1);
#pragma unroll
      for (int n = 0; n < 4; ++n) {
        int col = cbase + n * 16;
        int h = col >> 6, hd = col & 63;
        f16x4 vv = {(_Float16)acc[m][n][0], (_Float16)acc[m][n][1],
                    (_Float16)acc[m][n][2], (_Float16)acc[m][n][3]};
        *(f16x4*)(Vt + ((size_t)((b << 4) + h) * HD_ + hd) * S_ + s) = vv;
      }
    }
  } else {
    u16* dst = mode == 0 ? Qb : Kb;
    float scl = mode == 0 ? QSCALE : 1.0f;
#pragma unroll
    for (int m = 0; m < 4; ++m)
#pragma unroll
      for (int n = 0; n < 4; ++n) {
        int col = cbase + n * 16;
#pragma unroll
        for (int r = 0; r < 4; ++r) {
          int row = rbase + m * 16 + r;
          dst[(size_t)row * D_ + col] = f2bf(acc[m][n][r] * scl);
        }
      }
  }
}

// ---------------- fused causal flash attention, v7 (r9-exact: best measured, 119us) ----------------
__global__ __launch_bounds__(256) void attn_kernel(const u16* __restrict__ Qb, const u16* __restrict__ Kb,
                                                   const _Float16* __restrict__ Vt, u16* __restrict__ attnb) {
  __shared__ u16 Ks[2][64][LDP];       // [kv][hd]
  __shared__ _Float16 Vs[2][HD_][LDP]; // [hd][kv]
  const int tid = threadIdx.x;
  const int wave = tid >> 6, lane = tid & 63;
  const int l15 = lane & 15, lg = lane >> 4;
  const int lin = blockIdx.x;
  const int xcd = lin & 7, slot = lin >> 3;  // slot 0..127
  const int p = slot >> 3;                   // pair index 0..15
  const int bh = (slot & 7) * 8 + xcd;       // bh&7 == xcd
  const int b = bh >> 4, h = bh & 15;

  const int srow = tid >> 3;
  const int scol = (tid & 7) * 8;  // u16/f16 elems (16B)
  const u16* Kg = Kb + (size_t)(b * S_) * D_ + h * HD_;
  const _Float16* Vg = Vt + (size_t)bh * HD_ * S_;

  const f16x4 ones16 = {(_Float16)1.0f, (_Float16)1.0f, (_Float16)1.0f, (_Float16)1.0f};

#pragma unroll 1
  for (int phase = 0; phase < 2; ++phase) {
    const int qblk = phase == 0 ? (31 - p) : p;  // big half first
    const int q0b = qblk * 64;
    const int ntiles = qblk + 1;
    const int q0 = q0b + wave * 16;

    const u16* Qrow = Qb + (size_t)(b * S_ + q0 + l15) * D_ + h * HD_;
    bf16x8 qf0 = *(const bf16x8*)(Qrow + lg * 8);
    bf16x8 qf1 = *(const bf16x8*)(Qrow + 32 + lg * 8);

    float m = -1e30f;
    f32x4 o[4] = {};
    f32x4 osum = {};  // ones-MFMA row-sum accumulator: osum[r] == lsum for all r
    u32x4 kreg0, kreg1, vreg0, vreg1;

    __syncthreads();  // protect buf0 from previous phase's readers
    // prologue: tile 0 -> regs -> LDS buf0
    kreg0 = *(const u32x4*)(Kg + (size_t)(srow) * D_ + scol);
    kreg1 = *(const u32x4*)(Kg + (size_t)(32 + srow) * D_ + scol);
    vreg0 = *(const u32x4*)(Vg + (size_t)srow * S_ + scol);
    vreg1 = *(const u32x4*)(Vg + (size_t)(32 + srow) * S_ + scol);
    *(u32x4*)(&Ks[0][srow][scol]) = kreg0;
    *(u32x4*)(&Ks[0][32 + srow][scol]) = kreg1;
    *(u32x4*)(&Vs[0][srow][scol]) = vreg0;
    *(u32x4*)(&Vs[0][32 + srow][scol]) = vreg1;

#pragma unroll 1
    for (int t = 0; t < ntiles; ++t) {
      const int cur = t & 1;
      __syncthreads();  // tile t visible in buf[cur]
      if (t + 1 < ntiles) {
        int kv0n = (t + 1) * 64;
        kreg0 = *(const u32x4*)(Kg + (size_t)(kv0n + srow) * D_ + scol);
        kreg1 = *(const u32x4*)(Kg + (size_t)(kv0n + 32 + srow) * D_ + scol);
        vreg0 = *(const u32x4*)(Vg + (size_t)srow * S_ + kv0n + scol);
        vreg1 = *(const u32x4*)(Vg + (size_t)(32 + srow) * S_ + kv0n + scol);
      }
      // ---- QK^T: 4 subtiles of 16 kv ----
      f32x4 s[4];
      __builtin_amdgcn_s_setprio(1);
#pragma unroll
      for (int j = 0; j < 4; ++j) {
        bf16x8 kf0 = *(const bf16x8*)(&Ks[cur][j * 16 + l15][lg * 8]);
        bf16x8 kf1 = *(const bf16x8*)(&Ks[cur][j * 16 + l15][32 + lg * 8]);
        f32x4 z = {0.f, 0.f, 0.f, 0.f};
        z = __builtin_amdgcn_mfma_f32_16x16x32_bf16(kf0, qf0, z, 0, 0, 0);
        z = __builtin_amdgcn_mfma_f32_16x16x32_bf16(kf1, qf1, z, 0, 0, 0);
        s[j] = z;
      }
      __builtin_amdgcn_s_setprio(0);
      // ---- mask (diagonal tile only) ----
      if (t == ntiles - 1) {
        int qr = wave * 16 + l15;
#pragma unroll
        for (int j = 0; j < 4; ++j)
#pragma unroll
          for (int r = 0; r < 4; ++r)
            if (j * 16 + lg * 4 + r > qr) s[j][r] = -1e30f;
      }
      // ---- online softmax (max3 tree + one cross-lane reduce per 64 kv) ----
      float x0 = max3f(s[0][0], s[0][1], s[0][2]);
      float x1 = max3f(s[0][3], s[1][0], s[1][1]);
      float x2 = max3f(s[1][2], s[1][3], s[2][0]);
      float x3 = max3f(s[2][1], s[2][2], s[2][3]);
      float x4 = max3f(s[3][0], s[3][1], s[3][2]);
      float tmax = fmaxf(max3f(x0, x1, x2), max3f(x3, x4, s[3][3]));
      tmax = fmaxf(tmax, __shfl_xor(tmax, 16));
      tmax = fmaxf(tmax, __shfl_xor(tmax, 32));
      if (!__all(tmax - m <= 8.f)) {  // defer-max (T13)
        float nm = fmaxf(m, tmax);
        float alpha = exp2f(m - nm);
        m = nm;
        osum *= alpha;
#pragma unroll
        for (int hf = 0; hf < 4; ++hf) o[hf] *= alpha;
      }
      f16x4 pb[4];
#pragma unroll
      for (int j = 0; j < 4; ++j) {
        float p0 = exp2f(s[j][0] - m), p1 = exp2f(s[j][1] - m);
        float p2 = exp2f(s[j][2] - m), p3 = exp2f(s[j][3] - m);
        u32 lo = __builtin_bit_cast(u32, __builtin_amdgcn_cvt_pkrtz(p0, p1));
        u32 hi = __builtin_bit_cast(u32, __builtin_amdgcn_cvt_pkrtz(p2, p3));
        pb[j] = __builtin_bit_cast(f16x4, (u32x2){lo, hi});
      }
      // ---- PV + row-sum: o[hf] += V^T[hf] * P ; osum += 1 * P ----
      __builtin_amdgcn_s_setprio(1);
#pragma unroll
      for (int j = 0; j < 4; ++j) {
#pragma unroll
        for (int hf = 0; hf < 4; ++hf) {
          f16x4 vf = *(const f16x4*)(&Vs[cur][hf * 16 + l15][j * 16 + lg * 4]);
          o[hf] = __builtin_amdgcn_mfma_f32_16x16x16f16(vf, pb[j], o[hf], 0, 0, 0);
        }
        osum = __builtin_amdgcn_mfma_f32_16x16x16f16(ones16, pb[j], osum, 0, 0, 0);
      }
      __builtin_amdgcn_s_setprio(0);
      // ---- write tile t+1 into the other buffer (all waves passed top barrier) ----
      if (t + 1 < ntiles) {
        const int nxt = cur ^ 1;
        *(u32x4*)(&Ks[nxt][srow][scol]) = kreg0;
        *(u32x4*)(&Ks[nxt][32 + srow][scol]) = kreg1;
        *(u32x4*)(&Vs[nxt][srow][scol]) = vreg0;
        *(u32x4*)(&Vs[nxt][32 + srow][scol]) = vreg1;
      }
    }
    // ---- epilogue: normalize (osum[0] == row sum, per-lane uniform), store ----
    float inv = 1.0f / osum[0];
    u16* Orow = attnb + (size_t)(b * S_ + q0 + l15) * D_ + h * HD_ + lg * 4;
#pragma unroll
    for (int hf = 0; hf < 4; ++hf) {
      u16x4 ov = {f2bf(o[hf][0] * inv), f2bf(o[hf][1] * inv),
                  f2bf(o[hf][2] * inv), f2bf(o[hf][3] * inv)};
      *(u16x4*)(Orow + hf * 16) = ov;
    }
  }
}

// ---------------- output projection GEMM (fp32 out + bias, XCD-clustered swizzle) ----------------
__global__ __launch_bounds__(256) void out_gemm_kernel(const u16* __restrict__ attnb, const u16* __restrict__ Wot,
                                                       const float* __restrict__ bo, float* __restrict__ outp) {
  __shared__ u16 As[128 * 64];
  __shared__ u16 Bs[128 * 64];
  int lin = blockIdx.x;
  int xcd = lin & 7, pos = lin >> 3;  // pos in [0,64)
  int by = xcd * 8 + (pos >> 3);
  int bx = pos & 7;
  f32x4 acc[4][4] = {};
  int row0 = by * 128, col0 = bx * 128;
  gemm_main(attnb, Wot, As, Bs, row0, col0, acc);
  int lane = threadIdx.x & 63, wave = threadIdx.x >> 6;
  int wr = wave >> 1, wc = wave & 1, l15 = lane & 15, lg = lane >> 4;
  int rbase = row0 + wr * 64 + lg * 4, cbase = col0 + wc * 64 + l15;
#pragma unroll
  for (int n = 0; n < 4; ++n) {
    float bn = bo[cbase + n * 16];
#pragma unroll
    for (int m = 0; m < 4; ++m)
#pragma unroll
      for (int r = 0; r < 4; ++r)
        outp[(size_t)(rbase + m * 16 + r) * D_ + cbase + n * 16] = acc[m][n][r] + bn;
  }
}

extern "C" void kernel_launch(void* const* d_in, const int* in_sizes, int n_in,
                              void* d_out, int out_size, void* d_ws, size_t ws_size,
                              hipStream_t stream) {
  const float* x  = (const float*)d_in[0];
  const float* Wq = (const float*)d_in[1];
  const float* Wk = (const float*)d_in[2];
  const float* Wv = (const float*)d_in[3];
  const float* Wo = (const float*)d_in[4];
  const float* bo = (const float*)d_in[5];
  float* outp = (float*)d_out;

  char* ws = (char*)d_ws;
  u16* xb        = (u16*)(ws);                          // 16 MiB
  u16* Wqt       = (u16*)(ws + ((size_t)16 << 20));     // 2 MiB
  u16* Wkt       = (u16*)(ws + ((size_t)18 << 20));
  u16* Wvt       = (u16*)(ws + ((size_t)20 << 20));
  u16* Wot       = (u16*)(ws + ((size_t)22 << 20));
  u16* Qb        = (u16*)(ws + ((size_t)24 << 20));     // 16 MiB
  u16* Kb        = (u16*)(ws + ((size_t)40 << 20));     // 16 MiB
  _Float16* Vt   = (_Float16*)(ws + ((size_t)56 << 20));// 16 MiB
  u16* attnb     = (u16*)(ws + ((size_t)72 << 20));     // 16 MiB

  prep_kernel<<<dim3(9216), dim3(256), 0, stream>>>(x, xb, Wq, Wk, Wv, Wo, Wqt, Wkt, Wvt, Wot);
  qkv_gemm_kernel<<<dim3(1536), dim3(256), 0, stream>>>(xb, Wqt, Wkt, Wvt, Qb, Kb, Vt);
  attn_kernel<<<dim3(1024), dim3(256), 0, stream>>>(Qb, Kb, Vt, attnb);
  out_gemm_kernel<<<dim3(512), dim3(256), 0, stream>>>(attnb, Wot, bo, outp);
}

// Round 14
// 188.062 us; speedup vs baseline: 1.8837x; 1.1080x over previous
//
#include <hip/hip_runtime.h>

typedef unsigned short u16;
typedef unsigned int u32;
typedef __attribute__((ext_vector_type(4))) float f32x4;
typedef __attribute__((ext_vector_type(8))) __bf16 bf16x8;
typedef __attribute__((ext_vector_type(4))) _Float16 f16x4;
typedef __attribute__((ext_vector_type(4))) u16 u16x4;
typedef __attribute__((ext_vector_type(4))) u32 u32x4;
typedef __attribute__((ext_vector_type(2))) u32 u32x2;

#define D_ 1024
#define S_ 2048
#define B_ 4
#define H_ 16
#define HD_ 64
#define M_ 8192
#define LDP 72
#define QSCALE 0.18033688011112042591f /* 0.125 * log2(e) */

__device__ __forceinline__ u16 f2bf(float f) {
  u32 u = __float_as_uint(f);
  u += 0x7fffu + ((u >> 16) & 1u);
  return (u16)(u >> 16);
}

__device__ __forceinline__ float max3f(float a, float b, float c) {
  return fmaxf(fmaxf(a, b), c);  // clang fuses to v_max3_f32
}

// async 16B global->LDS DMA; LDS dest = wave-uniform base + lane*16 (linear!)
__device__ __forceinline__ void gload_lds16(const void* g, void* l) {
  __builtin_amdgcn_global_load_lds((const __attribute__((address_space(1))) void*)g,
                                   (__attribute__((address_space(3))) void*)l, 16, 0, 0);
}

// ---------------- fused prep: cast x (fp32->bf16) + transpose+cast weights ----------------
__global__ __launch_bounds__(256) void prep_kernel(const float* __restrict__ x, u16* __restrict__ xb,
                                                   const float* __restrict__ Wq, const float* __restrict__ Wk,
                                                   const float* __restrict__ Wv, const float* __restrict__ Wo,
                                                   u16* __restrict__ Wqt, u16* __restrict__ Wkt,
                                                   u16* __restrict__ Wvt, u16* __restrict__ Wot) {
  __shared__ float lds[64][65];
  int lin = blockIdx.x;
  if (lin < 8192) {
    int i = (lin * 256 + threadIdx.x) * 4;
    f32x4 v = *(const f32x4*)(x + i);
    u16x4 o = {f2bf(v[0]), f2bf(v[1]), f2bf(v[2]), f2bf(v[3])};
    *(u16x4*)(xb + i) = o;
    return;
  }
  int pos = lin - 8192;
  int z = pos >> 8, rem = pos & 255;
  const float* W = z == 0 ? Wq : z == 1 ? Wk : z == 2 ? Wv : Wo;
  u16* Wt       = z == 0 ? Wqt : z == 1 ? Wkt : z == 2 ? Wvt : Wot;
  int k0 = (rem >> 4) * 64, n0 = (rem & 15) * 64;
  int tr = threadIdx.x >> 6, tc = threadIdx.x & 63;
#pragma unroll
  for (int i = 0; i < 16; ++i)
    lds[tr + i * 4][tc] = W[(size_t)(k0 + tr + i * 4) * D_ + n0 + tc];
  __syncthreads();
#pragma unroll
  for (int i = 0; i < 16; ++i)
    Wt[(size_t)(n0 + tr + i * 4) * D_ + k0 + tc] = f2bf(lds[tc][tr + i * 4]);
}

// ---------------- shared 128x128 GEMM mainloop (global_load_lds staging, XOR swizzle) ----------------
__device__ __forceinline__ void gemm_main(const u16* __restrict__ A, const u16* __restrict__ Bt,
                                          u16* As, u16* Bs, int row0, int col0, f32x4 acc[4][4]) {
  const int tid = threadIdx.x;
  const int lane = tid & 63, wave = tid >> 6;
  const int wr = wave >> 1, wc = wave & 1;
  const int l15 = lane & 15, lg = lane >> 4;
  const int sr8 = lane >> 3;        // row within this wave's 8-row chunk (= r&7)
  const int scx = (lane & 7) ^ sr8; // pre-swizzled source k-chunk
#pragma unroll 1
  for (int k0 = 0; k0 < D_; k0 += 64) {
    // issue async stages: 4 wave-chunks of 8 rows for A and B each
#pragma unroll
    for (int it = 0; it < 4; ++it) {
      int rbase = (it * 4 + wave) * 8;
      int r = rbase + sr8;
      gload_lds16(A + (size_t)(row0 + r) * D_ + k0 + scx * 8, As + rbase * 64);
      gload_lds16(Bt + (size_t)(col0 + r) * D_ + k0 + scx * 8, Bs + rbase * 64);
    }
    __syncthreads();  // drains vmcnt -> DMA writes visible; syncs waves
#pragma unroll
    for (int kk = 0; kk < 64; kk += 32) {
      const int cb = kk >> 3;  // 0 or 4
      bf16x8 af[4], bf[4];
#pragma unroll
      for (int m = 0; m < 4; ++m) {
        int row = wr * 64 + m * 16 + l15;
        af[m] = *(const bf16x8*)(As + row * 64 + (((cb + lg) ^ (l15 & 7)) << 3));
      }
#pragma unroll
      for (int n = 0; n < 4; ++n) {
        int row = wc * 64 + n * 16 + l15;
        bf[n] = *(const bf16x8*)(Bs + row * 64 + (((cb + lg) ^ (l15 & 7)) << 3));
      }
#pragma unroll
      for (int m = 0; m < 4; ++m)
#pragma unroll
        for (int n = 0; n < 4; ++n)
          acc[m][n] = __builtin_amdgcn_mfma_f32_16x16x32_bf16(af[m], bf[n], acc[m][n], 0, 0, 0);
    }
    __syncthreads();  // readers done before next iteration's DMA writes
  }
}

// ---------------- QKV projection GEMM (1D grid, XCD-clustered swizzle) ----------------
__global__ __launch_bounds__(256) void qkv_gemm_kernel(const u16* __restrict__ xb,
                                                       const u16* __restrict__ Wqt, const u16* __restrict__ Wkt,
                                                       const u16* __restrict__ Wvt,
                                                       u16* __restrict__ Qb, u16* __restrict__ Kb,
                                                       _Float16* __restrict__ Vt) {
  __shared__ u16 As[128 * 64];
  __shared__ u16 Bs[128 * 64];
  int lin = blockIdx.x;
  int xcd = lin & 7, pos = lin >> 3;      // pos in [0,192)
  int mode = pos / 64;                    // z outer
  int rem = pos & 63;
  int by = xcd * 8 + (rem >> 3);          // row-panel
  int bx = rem & 7;                       // col-tile
  const u16* Bt = mode == 0 ? Wqt : mode == 1 ? Wkt : Wvt;
  f32x4 acc[4][4] = {};
  int row0 = by * 128, col0 = bx * 128;
  gemm_main(xb, Bt, As, Bs, row0, col0, acc);
  int lane = threadIdx.x & 63, wave = threadIdx.x >> 6;
  int wr = wave >> 1, wc = wave & 1, l15 = lane & 15, lg = lane >> 4;
  int rbase = row0 + wr * 64 + lg * 4, cbase = col0 + wc * 64 + l15;
  if (mode == 2) {
#pragma unroll
    for (int m = 0; m < 4; ++m) {
      int row = rbase + m * 16;
      int b = row >> 11, s = row & (S_ - 1);
#pragma unroll
      for (int n = 0; n < 4; ++n) {
        int col = cbase + n * 16;
        int h = col >> 6, hd = col & 63;
        f16x4 vv = {(_Float16)acc[m][n][0], (_Float16)acc[m][n][1],
                    (_Float16)acc[m][n][2], (_Float16)acc[m][n][3]};
        *(f16x4*)(Vt + ((size_t)((b << 4) + h) * HD_ + hd) * S_ + s) = vv;
      }
    }
  } else {
    u16* dst = mode == 0 ? Qb : Kb;
    float scl = mode == 0 ? QSCALE : 1.0f;
#pragma unroll
    for (int m = 0; m < 4; ++m)
#pragma unroll
      for (int n = 0; n < 4; ++n) {
        int col = cbase + n * 16;
#pragma unroll
        for (int r = 0; r < 4; ++r) {
          int row = rbase + m * 16 + r;
          dst[(size_t)row * D_ + col] = f2bf(acc[m][n][r] * scl);
        }
      }
  }
}

// ---------------- fused causal flash attention, v11: r12 body, NATURAL register budget ----------------
// Single K/V buffer (18KB LDS -> 8 blocks/CU cap), 2048 blocks (qblk x bh), LPT, XCD clustering.
// NO min-waves launch bound (r11/r12 lesson: forcing 8 waves/EU allocates 32 VGPR -> spills).
// Tile loop: [barrier: readers done] write(t) [barrier: visible] issue loads(t+1); compute(t).
__global__ __launch_bounds__(256) void attn_kernel(const u16* __restrict__ Qb, const u16* __restrict__ Kb,
                                                   const _Float16* __restrict__ Vt, u16* __restrict__ attnb) {
  __shared__ u16 Ks[64][LDP];       // [kv][hd]
  __shared__ _Float16 Vs[64][LDP];  // [hd][kv]
  const int tid = threadIdx.x;
  const int wave = tid >> 6, lane = tid & 63;
  const int l15 = lane & 15, lg = lane >> 4;
  const int lin = blockIdx.x;
  const int xcd = lin & 7, slot = lin >> 3;   // slot 0..255
  const int qblk = 31 - (slot >> 3);          // LPT: biggest first
  const int bh = (slot & 7) * 8 + xcd;        // bh&7 == xcd
  const int b = bh >> 4, h = bh & 15;
  const int ntiles = qblk + 1;
  const int q0 = qblk * 64 + wave * 16;

  const int srow = tid >> 3;
  const int scol = (tid & 7) * 8;  // u16/f16 elems (16B)
  const u16* Kg = Kb + (size_t)(b * S_) * D_ + h * HD_;
  const _Float16* Vg = Vt + (size_t)bh * HD_ * S_;

  const u16* Qrow = Qb + (size_t)(b * S_ + q0 + l15) * D_ + h * HD_;
  bf16x8 qf0 = *(const bf16x8*)(Qrow + lg * 8);
  bf16x8 qf1 = *(const bf16x8*)(Qrow + 32 + lg * 8);

  float m = -1e30f, lsum = 0.f;
  f32x4 o[4] = {};
  u32x4 kreg0, kreg1, vreg0, vreg1;

  // prologue: tile 0 -> regs
  kreg0 = *(const u32x4*)(Kg + (size_t)(srow) * D_ + scol);
  kreg1 = *(const u32x4*)(Kg + (size_t)(32 + srow) * D_ + scol);
  vreg0 = *(const u32x4*)(Vg + (size_t)srow * S_ + scol);
  vreg1 = *(const u32x4*)(Vg + (size_t)(32 + srow) * S_ + scol);

#pragma unroll 1
  for (int t = 0; t < ntiles; ++t) {
    __syncthreads();  // previous tile's readers done -> safe to overwrite
    *(u32x4*)(&Ks[srow][scol]) = kreg0;
    *(u32x4*)(&Ks[32 + srow][scol]) = kreg1;
    *(u32x4*)(&Vs[srow][scol]) = vreg0;
    *(u32x4*)(&Vs[32 + srow][scol]) = vreg1;
    __syncthreads();  // writes visible
    // issue global loads for tile t+1 (drain under compute)
    if (t + 1 < ntiles) {
      int kv0n = (t + 1) * 64;
      kreg0 = *(const u32x4*)(Kg + (size_t)(kv0n + srow) * D_ + scol);
      kreg1 = *(const u32x4*)(Kg + (size_t)(kv0n + 32 + srow) * D_ + scol);
      vreg0 = *(const u32x4*)(Vg + (size_t)srow * S_ + kv0n + scol);
      vreg1 = *(const u32x4*)(Vg + (size_t)(32 + srow) * S_ + kv0n + scol);
    }
    // ---- QK^T: 4 subtiles of 16 kv ----
    f32x4 s[4];
    __builtin_amdgcn_s_setprio(1);
#pragma unroll
    for (int j = 0; j < 4; ++j) {
      bf16x8 kf0 = *(const bf16x8*)(&Ks[j * 16 + l15][lg * 8]);
      bf16x8 kf1 = *(const bf16x8*)(&Ks[j * 16 + l15][32 + lg * 8]);
      f32x4 z = {0.f, 0.f, 0.f, 0.f};
      z = __builtin_amdgcn_mfma_f32_16x16x32_bf16(kf0, qf0, z, 0, 0, 0);
      z = __builtin_amdgcn_mfma_f32_16x16x32_bf16(kf1, qf1, z, 0, 0, 0);
      s[j] = z;
    }
    __builtin_amdgcn_s_setprio(0);
    // ---- mask (diagonal tile only) ----
    if (t == ntiles - 1) {
      int qr = wave * 16 + l15;
#pragma unroll
      for (int j = 0; j < 4; ++j)
#pragma unroll
        for (int r = 0; r < 4; ++r)
          if (j * 16 + lg * 4 + r > qr) s[j][r] = -1e30f;
    }
    // ---- online softmax (max3 tree + one cross-lane reduce per 64 kv) ----
    float x0 = max3f(s[0][0], s[0][1], s[0][2]);
    float x1 = max3f(s[0][3], s[1][0], s[1][1]);
    float x2 = max3f(s[1][2], s[1][3], s[2][0]);
    float x3 = max3f(s[2][1], s[2][2], s[2][3]);
    float x4 = max3f(s[3][0], s[3][1], s[3][2]);
    float tmax = fmaxf(max3f(x0, x1, x2), max3f(x3, x4, s[3][3]));
    tmax = fmaxf(tmax, __shfl_xor(tmax, 16));
    tmax = fmaxf(tmax, __shfl_xor(tmax, 32));
    if (!__all(tmax - m <= 8.f)) {  // defer-max (T13)
      float nm = fmaxf(m, tmax);
      float alpha = exp2f(m - nm);
      m = nm;
      lsum *= alpha;
#pragma unroll
      for (int hf = 0; hf < 4; ++hf) o[hf] *= alpha;
    }
    f16x4 pb[4];
#pragma unroll
    for (int j = 0; j < 4; ++j) {
      float p0 = exp2f(s[j][0] - m), p1 = exp2f(s[j][1] - m);
      float p2 = exp2f(s[j][2] - m), p3 = exp2f(s[j][3] - m);
      lsum += (p0 + p1) + (p2 + p3);
      u32 lo = __builtin_bit_cast(u32, __builtin_amdgcn_cvt_pkrtz(p0, p1));
      u32 hi = __builtin_bit_cast(u32, __builtin_amdgcn_cvt_pkrtz(p2, p3));
      pb[j] = __builtin_bit_cast(f16x4, (u32x2){lo, hi});
    }
    // ---- PV: o[hf] += V^T[hf] * P ----
    __builtin_amdgcn_s_setprio(1);
#pragma unroll
    for (int j = 0; j < 4; ++j) {
#pragma unroll
      for (int hf = 0; hf < 4; ++hf) {
        f16x4 vf = *(const f16x4*)(&Vs[hf * 16 + l15][j * 16 + lg * 4]);
        o[hf] = __builtin_amdgcn_mfma_f32_16x16x16f16(vf, pb[j], o[hf], 0, 0, 0);
      }
    }
    __builtin_amdgcn_s_setprio(0);
  }
  // ---- epilogue: reduce lsum across lane-groups, normalize, store ----
  lsum += __shfl_xor(lsum, 16);
  lsum += __shfl_xor(lsum, 32);
  float inv = 1.0f / lsum;
  u16* Orow = attnb + (size_t)(b * S_ + q0 + l15) * D_ + h * HD_ + lg * 4;
#pragma unroll
  for (int hf = 0; hf < 4; ++hf) {
    u16x4 ov = {f2bf(o[hf][0] * inv), f2bf(o[hf][1] * inv),
                f2bf(o[hf][2] * inv), f2bf(o[hf][3] * inv)};
    *(u16x4*)(Orow + hf * 16) = ov;
  }
}

// ---------------- output projection GEMM (fp32 out + bias, XCD-clustered swizzle) ----------------
__global__ __launch_bounds__(256) void out_gemm_kernel(const u16* __restrict__ attnb, const u16* __restrict__ Wot,
                                                       const float* __restrict__ bo, float* __restrict__ outp) {
  __shared__ u16 As[128 * 64];
  __shared__ u16 Bs[128 * 64];
  int lin = blockIdx.x;
  int xcd = lin & 7, pos = lin >> 3;  // pos in [0,64)
  int by = xcd * 8 + (pos >> 3);
  int bx = pos & 7;
  f32x4 acc[4][4] = {};
  int row0 = by * 128, col0 = bx * 128;
  gemm_main(attnb, Wot, As, Bs, row0, col0, acc);
  int lane = threadIdx.x & 63, wave = threadIdx.x >> 6;
  int wr = wave >> 1, wc = wave & 1, l15 = lane & 15, lg = lane >> 4;
  int rbase = row0 + wr * 64 + lg * 4, cbase = col0 + wc * 64 + l15;
#pragma unroll
  for (int n = 0; n < 4; ++n) {
    float bn = bo[cbase + n * 16];
#pragma unroll
    for (int m = 0; m < 4; ++m)
#pragma unroll
      for (int r = 0; r < 4; ++r)
        outp[(size_t)(rbase + m * 16 + r) * D_ + cbase + n * 16] = acc[m][n][r] + bn;
  }
}

extern "C" void kernel_launch(void* const* d_in, const int* in_sizes, int n_in,
                              void* d_out, int out_size, void* d_ws, size_t ws_size,
                              hipStream_t stream) {
  const float* x  = (const float*)d_in[0];
  const float* Wq = (const float*)d_in[1];
  const float* Wk = (const float*)d_in[2];
  const float* Wv = (const float*)d_in[3];
  const float* Wo = (const float*)d_in[4];
  const float* bo = (const float*)d_in[5];
  float* outp = (float*)d_out;

  char* ws = (char*)d_ws;
  u16* xb        = (u16*)(ws);                          // 16 MiB
  u16* Wqt       = (u16*)(ws + ((size_t)16 << 20));     // 2 MiB
  u16* Wkt       = (u16*)(ws + ((size_t)18 << 20));
  u16* Wvt       = (u16*)(ws + ((size_t)20 << 20));
  u16* Wot       = (u16*)(ws + ((size_t)22 << 20));
  u16* Qb        = (u16*)(ws + ((size_t)24 << 20));     // 16 MiB
  u16* Kb        = (u16*)(ws + ((size_t)40 << 20));     // 16 MiB
  _Float16* Vt   = (_Float16*)(ws + ((size_t)56 << 20));// 16 MiB
  u16* attnb     = (u16*)(ws + ((size_t)72 << 20));     // 16 MiB

  prep_kernel<<<dim3(9216), dim3(256), 0, stream>>>(x, xb, Wq, Wk, Wv, Wo, Wqt, Wkt, Wvt, Wot);
  qkv_gemm_kernel<<<dim3(1536), dim3(256), 0, stream>>>(xb, Wqt, Wkt, Wvt, Qb, Kb, Vt);
  attn_kernel<<<dim3(2048), dim3(256), 0, stream>>>(Qb, Kb, Vt, attnb);
  out_gemm_kernel<<<dim3(512), dim3(256), 0, stream>>>(attnb, Wot, bo, outp);
}

// Round 15
// 186.302 us; speedup vs baseline: 1.9015x; 1.0094x over previous
//
#include <hip/hip_runtime.h>

typedef unsigned short u16;
typedef unsigned int u32;
typedef __attribute__((ext_vector_type(4))) float f32x4;
typedef __attribute__((ext_vector_type(8))) __bf16 bf16x8;
typedef __attribute__((ext_vector_type(4))) _Float16 f16x4;
typedef __attribute__((ext_vector_type(4))) u16 u16x4;
typedef __attribute__((ext_vector_type(4))) u32 u32x4;
typedef __attribute__((ext_vector_type(2))) u32 u32x2;

#define D_ 1024
#define S_ 2048
#define B_ 4
#define H_ 16
#define HD_ 64
#define M_ 8192
#define LDP 72
#define QSCALE 0.18033688011112042591f /* 0.125 * log2(e) */

__device__ __forceinline__ u16 f2bf(float f) {
  u32 u = __float_as_uint(f);
  u += 0x7fffu + ((u >> 16) & 1u);
  return (u16)(u >> 16);
}

__device__ __forceinline__ float max3f(float a, float b, float c) {
  return fmaxf(fmaxf(a, b), c);  // clang fuses to v_max3_f32
}

// async 16B global->LDS DMA; LDS dest = wave-uniform base + lane*16 (linear!)
__device__ __forceinline__ void gload_lds16(const void* g, void* l) {
  __builtin_amdgcn_global_load_lds((const __attribute__((address_space(1))) void*)g,
                                   (__attribute__((address_space(3))) void*)l, 16, 0, 0);
}

// ---------------- fused prep: cast x (fp32->bf16) + transpose+cast weights ----------------
__global__ __launch_bounds__(256) void prep_kernel(const float* __restrict__ x, u16* __restrict__ xb,
                                                   const float* __restrict__ Wq, const float* __restrict__ Wk,
                                                   const float* __restrict__ Wv, const float* __restrict__ Wo,
                                                   u16* __restrict__ Wqt, u16* __restrict__ Wkt,
                                                   u16* __restrict__ Wvt, u16* __restrict__ Wot) {
  __shared__ float lds[64][65];
  int lin = blockIdx.x;
  if (lin < 8192) {
    int i = (lin * 256 + threadIdx.x) * 4;
    f32x4 v = *(const f32x4*)(x + i);
    u16x4 o = {f2bf(v[0]), f2bf(v[1]), f2bf(v[2]), f2bf(v[3])};
    *(u16x4*)(xb + i) = o;
    return;
  }
  int pos = lin - 8192;
  int z = pos >> 8, rem = pos & 255;
  const float* W = z == 0 ? Wq : z == 1 ? Wk : z == 2 ? Wv : Wo;
  u16* Wt       = z == 0 ? Wqt : z == 1 ? Wkt : z == 2 ? Wvt : Wot;
  int k0 = (rem >> 4) * 64, n0 = (rem & 15) * 64;
  int tr = threadIdx.x >> 6, tc = threadIdx.x & 63;
#pragma unroll
  for (int i = 0; i < 16; ++i)
    lds[tr + i * 4][tc] = W[(size_t)(k0 + tr + i * 4) * D_ + n0 + tc];
  __syncthreads();
#pragma unroll
  for (int i = 0; i < 16; ++i)
    Wt[(size_t)(n0 + tr + i * 4) * D_ + k0 + tc] = f2bf(lds[tc][tr + i * 4]);
}

// ---------------- shared 128x128 GEMM mainloop (global_load_lds staging, XOR swizzle) ----------------
__device__ __forceinline__ void gemm_main(const u16* __restrict__ A, const u16* __restrict__ Bt,
                                          u16* As, u16* Bs, int row0, int col0, f32x4 acc[4][4]) {
  const int tid = threadIdx.x;
  const int lane = tid & 63, wave = tid >> 6;
  const int wr = wave >> 1, wc = wave & 1;
  const int l15 = lane & 15, lg = lane >> 4;
  const int sr8 = lane >> 3;        // row within this wave's 8-row chunk (= r&7)
  const int scx = (lane & 7) ^ sr8; // pre-swizzled source k-chunk
#pragma unroll 1
  for (int k0 = 0; k0 < D_; k0 += 64) {
    // issue async stages: 4 wave-chunks of 8 rows for A and B each
#pragma unroll
    for (int it = 0; it < 4; ++it) {
      int rbase = (it * 4 + wave) * 8;
      int r = rbase + sr8;
      gload_lds16(A + (size_t)(row0 + r) * D_ + k0 + scx * 8, As + rbase * 64);
      gload_lds16(Bt + (size_t)(col0 + r) * D_ + k0 + scx * 8, Bs + rbase * 64);
    }
    __syncthreads();  // drains vmcnt -> DMA writes visible; syncs waves
#pragma unroll
    for (int kk = 0; kk < 64; kk += 32) {
      const int cb = kk >> 3;  // 0 or 4
      bf16x8 af[4], bf[4];
#pragma unroll
      for (int m = 0; m < 4; ++m) {
        int row = wr * 64 + m * 16 + l15;
        af[m] = *(const bf16x8*)(As + row * 64 + (((cb + lg) ^ (l15 & 7)) << 3));
      }
#pragma unroll
      for (int n = 0; n < 4; ++n) {
        int row = wc * 64 + n * 16 + l15;
        bf[n] = *(const bf16x8*)(Bs + row * 64 + (((cb + lg) ^ (l15 & 7)) << 3));
      }
#pragma unroll
      for (int m = 0; m < 4; ++m)
#pragma unroll
        for (int n = 0; n < 4; ++n)
          acc[m][n] = __builtin_amdgcn_mfma_f32_16x16x32_bf16(af[m], bf[n], acc[m][n], 0, 0, 0);
    }
    __syncthreads();  // readers done before next iteration's DMA writes
  }
}

// ---------------- QKV projection GEMM (1D grid, XCD-clustered swizzle) ----------------
__global__ __launch_bounds__(256) void qkv_gemm_kernel(const u16* __restrict__ xb,
                                                       const u16* __restrict__ Wqt, const u16* __restrict__ Wkt,
                                                       const u16* __restrict__ Wvt,
                                                       u16* __restrict__ Qb, u16* __restrict__ Kb,
                                                       _Float16* __restrict__ Vt) {
  __shared__ u16 As[128 * 64];
  __shared__ u16 Bs[128 * 64];
  int lin = blockIdx.x;
  int xcd = lin & 7, pos = lin >> 3;      // pos in [0,192)
  int mode = pos / 64;                    // z outer
  int rem = pos & 63;
  int by = xcd * 8 + (rem >> 3);          // row-panel
  int bx = rem & 7;                       // col-tile
  const u16* Bt = mode == 0 ? Wqt : mode == 1 ? Wkt : Wvt;
  f32x4 acc[4][4] = {};
  int row0 = by * 128, col0 = bx * 128;
  gemm_main(xb, Bt, As, Bs, row0, col0, acc);
  int lane = threadIdx.x & 63, wave = threadIdx.x >> 6;
  int wr = wave >> 1, wc = wave & 1, l15 = lane & 15, lg = lane >> 4;
  int rbase = row0 + wr * 64 + lg * 4, cbase = col0 + wc * 64 + l15;
  if (mode == 2) {
#pragma unroll
    for (int m = 0; m < 4; ++m) {
      int row = rbase + m * 16;
      int b = row >> 11, s = row & (S_ - 1);
#pragma unroll
      for (int n = 0; n < 4; ++n) {
        int col = cbase + n * 16;
        int h = col >> 6, hd = col & 63;
        f16x4 vv = {(_Float16)acc[m][n][0], (_Float16)acc[m][n][1],
                    (_Float16)acc[m][n][2], (_Float16)acc[m][n][3]};
        *(f16x4*)(Vt + ((size_t)((b << 4) + h) * HD_ + hd) * S_ + s) = vv;
      }
    }
  } else {
    u16* dst = mode == 0 ? Qb : Kb;
    float scl = mode == 0 ? QSCALE : 1.0f;
#pragma unroll
    for (int m = 0; m < 4; ++m)
#pragma unroll
      for (int n = 0; n < 4; ++n) {
        int col = cbase + n * 16;
#pragma unroll
        for (int r = 0; r < 4; ++r) {
          int row = rbase + m * 16 + r;
          dst[(size_t)row * D_ + col] = f2bf(acc[m][n][r] * scl);
        }
      }
  }
}

// ---------------- fused causal flash attention, v12: r14 body + MFMA row-sum + ptr-increment staging ----------------
// Single K/V buffer (18KB LDS), 2048 blocks (qblk x bh), LPT, XCD clustering, natural VGPR.
// VALU cuts vs r14: lsum via ones-MFMA (idle pipe; -12 adds -2 shfl/tile),
// staging pointers advance by constant strides (-4x 64-bit addr builds/tile).
__global__ __launch_bounds__(256) void attn_kernel(const u16* __restrict__ Qb, const u16* __restrict__ Kb,
                                                   const _Float16* __restrict__ Vt, u16* __restrict__ attnb) {
  __shared__ u16 Ks[64][LDP];       // [kv][hd]
  __shared__ _Float16 Vs[64][LDP];  // [hd][kv]
  const int tid = threadIdx.x;
  const int wave = tid >> 6, lane = tid & 63;
  const int l15 = lane & 15, lg = lane >> 4;
  const int lin = blockIdx.x;
  const int xcd = lin & 7, slot = lin >> 3;   // slot 0..255
  const int qblk = 31 - (slot >> 3);          // LPT: biggest first
  const int bh = (slot & 7) * 8 + xcd;        // bh&7 == xcd
  const int b = bh >> 4, h = bh & 15;
  const int ntiles = qblk + 1;
  const int q0 = qblk * 64 + wave * 16;

  const int srow = tid >> 3;
  const int scol = (tid & 7) * 8;  // u16/f16 elems (16B)
  const u16* Kg = Kb + (size_t)(b * S_) * D_ + h * HD_;
  const _Float16* Vg = Vt + (size_t)bh * HD_ * S_;

  // staging pointers (advance by constant strides each tile)
  const u16* Kp0 = Kg + (size_t)srow * D_ + scol;
  const u16* Kp1 = Kg + (size_t)(32 + srow) * D_ + scol;
  const _Float16* Vp0 = Vg + (size_t)srow * S_ + scol;
  const _Float16* Vp1 = Vg + (size_t)(32 + srow) * S_ + scol;

  const u16* Qrow = Qb + (size_t)(b * S_ + q0 + l15) * D_ + h * HD_;
  bf16x8 qf0 = *(const bf16x8*)(Qrow + lg * 8);
  bf16x8 qf1 = *(const bf16x8*)(Qrow + 32 + lg * 8);

  float m = -1e30f;
  f32x4 o[4] = {};
  f32x4 osum = {};  // ones-MFMA row-sum: osum[r] == row sum (all r equal)
  const f16x4 ones16 = {(_Float16)1.0f, (_Float16)1.0f, (_Float16)1.0f, (_Float16)1.0f};
  u32x4 kreg0, kreg1, vreg0, vreg1;

  // prologue: tile 0 -> regs
  kreg0 = *(const u32x4*)(Kp0);
  kreg1 = *(const u32x4*)(Kp1);
  vreg0 = *(const u32x4*)(Vp0);
  vreg1 = *(const u32x4*)(Vp1);
  Kp0 += 64 * D_; Kp1 += 64 * D_; Vp0 += 64; Vp1 += 64;

#pragma unroll 1
  for (int t = 0; t < ntiles; ++t) {
    __syncthreads();  // previous tile's readers done -> safe to overwrite
    *(u32x4*)(&Ks[srow][scol]) = kreg0;
    *(u32x4*)(&Ks[32 + srow][scol]) = kreg1;
    *(u32x4*)(&Vs[srow][scol]) = vreg0;
    *(u32x4*)(&Vs[32 + srow][scol]) = vreg1;
    __syncthreads();  // writes visible
    // issue global loads for tile t+1 (drain under compute)
    if (t + 1 < ntiles) {
      kreg0 = *(const u32x4*)(Kp0);
      kreg1 = *(const u32x4*)(Kp1);
      vreg0 = *(const u32x4*)(Vp0);
      vreg1 = *(const u32x4*)(Vp1);
      Kp0 += 64 * D_; Kp1 += 64 * D_; Vp0 += 64; Vp1 += 64;
    }
    // ---- QK^T: 4 subtiles of 16 kv ----
    f32x4 s[4];
    __builtin_amdgcn_s_setprio(1);
#pragma unroll
    for (int j = 0; j < 4; ++j) {
      bf16x8 kf0 = *(const bf16x8*)(&Ks[j * 16 + l15][lg * 8]);
      bf16x8 kf1 = *(const bf16x8*)(&Ks[j * 16 + l15][32 + lg * 8]);
      f32x4 z = {0.f, 0.f, 0.f, 0.f};
      z = __builtin_amdgcn_mfma_f32_16x16x32_bf16(kf0, qf0, z, 0, 0, 0);
      z = __builtin_amdgcn_mfma_f32_16x16x32_bf16(kf1, qf1, z, 0, 0, 0);
      s[j] = z;
    }
    __builtin_amdgcn_s_setprio(0);
    // ---- mask (diagonal tile only) ----
    if (t == ntiles - 1) {
      int qr = wave * 16 + l15;
#pragma unroll
      for (int j = 0; j < 4; ++j)
#pragma unroll
        for (int r = 0; r < 4; ++r)
          if (j * 16 + lg * 4 + r > qr) s[j][r] = -1e30f;
    }
    // ---- online softmax (max3 tree + one cross-lane reduce per 64 kv) ----
    float x0 = max3f(s[0][0], s[0][1], s[0][2]);
    float x1 = max3f(s[0][3], s[1][0], s[1][1]);
    float x2 = max3f(s[1][2], s[1][3], s[2][0]);
    float x3 = max3f(s[2][1], s[2][2], s[2][3]);
    float x4 = max3f(s[3][0], s[3][1], s[3][2]);
    float tmax = fmaxf(max3f(x0, x1, x2), max3f(x3, x4, s[3][3]));
    tmax = fmaxf(tmax, __shfl_xor(tmax, 16));
    tmax = fmaxf(tmax, __shfl_xor(tmax, 32));
    if (!__all(tmax - m <= 8.f)) {  // defer-max (T13)
      float nm = fmaxf(m, tmax);
      float alpha = exp2f(m - nm);
      m = nm;
      osum *= alpha;
#pragma unroll
      for (int hf = 0; hf < 4; ++hf) o[hf] *= alpha;
    }
    f16x4 pb[4];
#pragma unroll
    for (int j = 0; j < 4; ++j) {
      float p0 = exp2f(s[j][0] - m), p1 = exp2f(s[j][1] - m);
      float p2 = exp2f(s[j][2] - m), p3 = exp2f(s[j][3] - m);
      u32 lo = __builtin_bit_cast(u32, __builtin_amdgcn_cvt_pkrtz(p0, p1));
      u32 hi = __builtin_bit_cast(u32, __builtin_amdgcn_cvt_pkrtz(p2, p3));
      pb[j] = __builtin_bit_cast(f16x4, (u32x2){lo, hi});
    }
    // ---- PV + row-sum: o[hf] += V^T[hf] * P ; osum += 1 * P ----
    __builtin_amdgcn_s_setprio(1);
#pragma unroll
    for (int j = 0; j < 4; ++j) {
#pragma unroll
      for (int hf = 0; hf < 4; ++hf) {
        f16x4 vf = *(const f16x4*)(&Vs[hf * 16 + l15][j * 16 + lg * 4]);
        o[hf] = __builtin_amdgcn_mfma_f32_16x16x16f16(vf, pb[j], o[hf], 0, 0, 0);
      }
      osum = __builtin_amdgcn_mfma_f32_16x16x16f16(ones16, pb[j], osum, 0, 0, 0);
    }
    __builtin_amdgcn_s_setprio(0);
  }
  // ---- epilogue: normalize (osum[0] == row sum, per-lane uniform), store ----
  float inv = 1.0f / osum[0];
  u16* Orow = attnb + (size_t)(b * S_ + q0 + l15) * D_ + h * HD_ + lg * 4;
#pragma unroll
  for (int hf = 0; hf < 4; ++hf) {
    u16x4 ov = {f2bf(o[hf][0] * inv), f2bf(o[hf][1] * inv),
                f2bf(o[hf][2] * inv), f2bf(o[hf][3] * inv)};
    *(u16x4*)(Orow + hf * 16) = ov;
  }
}

// ---------------- output projection GEMM (fp32 out + bias, XCD-clustered swizzle) ----------------
__global__ __launch_bounds__(256) void out_gemm_kernel(const u16* __restrict__ attnb, const u16* __restrict__ Wot,
                                                       const float* __restrict__ bo, float* __restrict__ outp) {
  __shared__ u16 As[128 * 64];
  __shared__ u16 Bs[128 * 64];
  int lin = blockIdx.x;
  int xcd = lin & 7, pos = lin >> 3;  // pos in [0,64)
  int by = xcd * 8 + (pos >> 3);
  int bx = pos & 7;
  f32x4 acc[4][4] = {};
  int row0 = by * 128, col0 = bx * 128;
  gemm_main(attnb, Wot, As, Bs, row0, col0, acc);
  int lane = threadIdx.x & 63, wave = threadIdx.x >> 6;
  int wr = wave >> 1, wc = wave & 1, l15 = lane & 15, lg = lane >> 4;
  int rbase = row0 + wr * 64 + lg * 4, cbase = col0 + wc * 64 + l15;
#pragma unroll
  for (int n = 0; n < 4; ++n) {
    float bn = bo[cbase + n * 16];
#pragma unroll
    for (int m = 0; m < 4; ++m)
#pragma unroll
      for (int r = 0; r < 4; ++r)
        outp[(size_t)(rbase + m * 16 + r) * D_ + cbase + n * 16] = acc[m][n][r] + bn;
  }
}

extern "C" void kernel_launch(void* const* d_in, const int* in_sizes, int n_in,
                              void* d_out, int out_size, void* d_ws, size_t ws_size,
                              hipStream_t stream) {
  const float* x  = (const float*)d_in[0];
  const float* Wq = (const float*)d_in[1];
  const float* Wk = (const float*)d_in[2];
  const float* Wv = (const float*)d_in[3];
  const float* Wo = (const float*)d_in[4];
  const float* bo = (const float*)d_in[5];
  float* outp = (float*)d_out;

  char* ws = (char*)d_ws;
  u16* xb        = (u16*)(ws);                          // 16 MiB
  u16* Wqt       = (u16*)(ws + ((size_t)16 << 20));     // 2 MiB
  u16* Wkt       = (u16*)(ws + ((size_t)18 << 20));
  u16* Wvt       = (u16*)(ws + ((size_t)20 << 20));
  u16* Wot       = (u16*)(ws + ((size_t)22 << 20));
  u16* Qb        = (u16*)(ws + ((size_t)24 << 20));     // 16 MiB
  u16* Kb        = (u16*)(ws + ((size_t)40 << 20));     // 16 MiB
  _Float16* Vt   = (_Float16*)(ws + ((size_t)56 << 20));// 16 MiB
  u16* attnb     = (u16*)(ws + ((size_t)72 << 20));     // 16 MiB

  prep_kernel<<<dim3(9216), dim3(256), 0, stream>>>(x, xb, Wq, Wk, Wv, Wo, Wqt, Wkt, Wvt, Wot);
  qkv_gemm_kernel<<<dim3(1536), dim3(256), 0, stream>>>(xb, Wqt, Wkt, Wvt, Qb, Kb, Vt);
  attn_kernel<<<dim3(2048), dim3(256), 0, stream>>>(Qb, Kb, Vt, attnb);
  out_gemm_kernel<<<dim3(512), dim3(256), 0, stream>>>(attnb, Wot, bo, outp);
}